// Round 6
// baseline (365.021 us; speedup 1.0000x reference)
//
#include <hip/hip_runtime.h>

#define SEQ 2048
#define DMODEL 2048
#define NHEADS 16
#define DKH 128

typedef __bf16 bf16;
typedef __attribute__((ext_vector_type(8))) __bf16 bf16x8;
typedef __attribute__((ext_vector_type(4))) __bf16 bf16x4;
typedef __attribute__((ext_vector_type(4))) float f32x4;

#define AS1 __attribute__((address_space(1)))
#define AS3 __attribute__((address_space(3)))

__device__ __forceinline__ void async_copy16(const void* g, void* l) {
  __builtin_amdgcn_global_load_lds((AS1 void*)(unsigned long long)g,
                                   (AS3 void*)l, 16, 0, 0);
}

// XOR-swizzle for 64-wide (8-chunk) LDS rows: slot = chunk ^ (row&7)
__device__ __forceinline__ int swz(int chunk, int row) {
  return (chunk ^ (row & 7)) << 3;
}
// XOR-swizzle for 128-wide (16-chunk) LDS rows: slot = chunk ^ (row&15)
__device__ __forceinline__ int swz16(int chunk, int row) {
  return (chunk ^ (row & 15)) << 3;
}

// ---------------------------------------------------------------------------
// Generic bf16 GEMM, "BT" pattern: C[m,n] = scale * sum_k A[m,k]*B[n,k] (+bias[n])
// 128x128 tile, BK=64, 4 waves of 64x64 via 16x16x32 MFMA, swizzled LDS.
// If CT != nullptr and blockIdx.z == 2, writes C TRANSPOSED to CT [N][M]
// instead of C (used to emit v^T directly from the projection).
// ---------------------------------------------------------------------------
template <typename OutT, bool BIAS>
__global__ __launch_bounds__(256) void gemm_bt(
    const bf16* __restrict__ A, const bf16* __restrict__ B,
    const float* __restrict__ bias, OutT* __restrict__ C,
    int M, int N, int K, int lda, int ldb, int ldo, float scale,
    long long sA, long long sB, long long sC, long long sBias,
    bf16* __restrict__ CT) {
  A += (long long)blockIdx.z * sA;
  B += (long long)blockIdx.z * sB;
  C += (long long)blockIdx.z * sC;
  const float* biasp = BIAS ? (bias + (long long)blockIdx.z * sBias) : nullptr;

  const int m0 = blockIdx.y * 128;
  const int n0 = blockIdx.x * 128;

  __shared__ __align__(16) bf16 As[128 * 64];
  __shared__ __align__(16) bf16 Bs[128 * 64];

  const int tid = threadIdx.x;
  const int wave = tid >> 6;
  const int lane = tid & 63;
  const int srow = wave * 8 + (lane >> 3);
  const int scol = ((lane & 7) ^ (lane >> 3)) * 8;  // swizzled source chunk
  const int wr = (wave >> 1) * 64;
  const int wc = (wave & 1) * 64;
  const int lr = lane & 15;
  const int quad = lane >> 4;

  const bf16* ag = A + (long long)(m0 + srow) * lda + scol;
  const bf16* bg = B + (long long)(n0 + srow) * ldb + scol;

  f32x4 acc[4][4];
#pragma unroll
  for (int i = 0; i < 4; ++i)
#pragma unroll
    for (int j = 0; j < 4; ++j) {
      acc[i][j][0] = 0.f; acc[i][j][1] = 0.f;
      acc[i][j][2] = 0.f; acc[i][j][3] = 0.f;
    }

  for (int kt = 0; kt < K; kt += 64) {
#pragma unroll
    for (int i = 0; i < 4; ++i) {
      async_copy16(ag + kt + (long long)i * 32 * lda, As + (i * 32 + wave * 8) * 64);
      async_copy16(bg + kt + (long long)i * 32 * ldb, Bs + (i * 32 + wave * 8) * 64);
    }
    __syncthreads();
#pragma unroll
    for (int kk = 0; kk < 64; kk += 32) {
      bf16x8 af[4], bfr[4];
#pragma unroll
      for (int i = 0; i < 4; ++i) {
        const int ra = wr + i * 16 + lr;
        const int rb = wc + i * 16 + lr;
        af[i]  = *(const bf16x8*)(As + ra * 64 + swz((kk >> 3) + quad, ra));
        bfr[i] = *(const bf16x8*)(Bs + rb * 64 + swz((kk >> 3) + quad, rb));
      }
#pragma unroll
      for (int i = 0; i < 4; ++i)
#pragma unroll
        for (int j = 0; j < 4; ++j)
          acc[i][j] = __builtin_amdgcn_mfma_f32_16x16x32_bf16(af[i], bfr[j], acc[i][j], 0, 0, 0);
    }
    __syncthreads();
  }

  if (BIAS && CT != nullptr && blockIdx.z == 2) {
    // transposed epilogue: CT[n][m], 8B (bf16x4) stores along m
#pragma unroll
    for (int j = 0; j < 4; ++j) {
      const int n = n0 + wc + j * 16 + lr;
      const float bv = biasp[n];
#pragma unroll
      for (int i = 0; i < 4; ++i) {
        const int mb = m0 + wr + i * 16 + quad * 4;
        bf16x4 o;
#pragma unroll
        for (int r = 0; r < 4; ++r) o[r] = (bf16)(acc[i][j][r] * scale + bv);
        *(bf16x4*)(CT + (long long)n * SEQ + mb) = o;
      }
    }
    return;
  }

#pragma unroll
  for (int j = 0; j < 4; ++j) {
    const int n = n0 + wc + j * 16 + lr;
    const float bv = BIAS ? biasp[n] : 0.f;
#pragma unroll
    for (int i = 0; i < 4; ++i) {
      const int mb = m0 + wr + i * 16 + quad * 4;
#pragma unroll
      for (int r = 0; r < 4; ++r)
        C[(long long)(mb + r) * ldo + n] = (OutT)(acc[i][j][r] * scale + bv);
    }
  }
}

// ---------------------------------------------------------------------------
// QK^T -> E = exp(score/sqrt(dk)) bf16 + per-column (over s) partial sums.
// A-tile 128x128 (32KB) resident; loop 8 B-tiles of 64 rows (16KB) over a
// 512-wide strip. LDS 48KB -> 3 blocks/CU. grid (4, 16, 16).
// ---------------------------------------------------------------------------
__global__ __launch_bounds__(256) void qk_exp(
    const bf16* __restrict__ q, const bf16* __restrict__ k,
    bf16* __restrict__ E, float* __restrict__ lpart) {
  const int h = blockIdx.z;
  const int m0 = blockIdx.y * 128;
  const int nstrip = blockIdx.x * 512;
  const bf16* A = q + (long long)h * DKH;
  const bf16* B = k + (long long)h * DKH;
  bf16* C = E + (long long)h * SEQ * SEQ;

  __shared__ __align__(16) bf16 As[128 * 128];  // 32KB
  __shared__ __align__(16) bf16 Bs[64 * 128];   // 16KB

  const int tid = threadIdx.x;
  const int wave = tid >> 6;
  const int lane = tid & 63;
  const int wr = (wave >> 1) * 64;  // A-row half
  const int wc = (wave & 1) * 32;   // B-col quarter (of 64)
  const int lr = lane & 15;
  const int quad = lane >> 4;
  const float scale = 0.08838834764831845f;  // 1/sqrt(128)

  // stage A-tile once (resident across all 8 B-tiles)
#pragma unroll
  for (int it = 0; it < 8; ++it) {
    const int row = wave * 32 + it * 4 + (lane >> 4);
    const int chunk = (lane & 15) ^ (row & 15);
    async_copy16(A + (long long)(m0 + row) * DMODEL + chunk * 8,
                 As + (wave * 32 + it * 4) * 128);
  }

  for (int nt = 0; nt < 8; ++nt) {
    if (nt) __syncthreads();  // protect Bs while other waves still read
#pragma unroll
    for (int it = 0; it < 4; ++it) {
      const int row = wave * 16 + it * 4 + (lane >> 4);
      const int chunk = (lane & 15) ^ (row & 15);
      async_copy16(B + (long long)(nstrip + nt * 64 + row) * DMODEL + chunk * 8,
                   Bs + (wave * 16 + it * 4) * 128);
    }
    __syncthreads();  // drains A (nt=0) and B staging

    f32x4 acc[4][2];
#pragma unroll
    for (int i = 0; i < 4; ++i)
#pragma unroll
      for (int j = 0; j < 2; ++j) {
        acc[i][j][0] = 0.f; acc[i][j][1] = 0.f;
        acc[i][j][2] = 0.f; acc[i][j][3] = 0.f;
      }

#pragma unroll
    for (int kk = 0; kk < 128; kk += 32) {
      bf16x8 af[4], bfr[2];
#pragma unroll
      for (int i = 0; i < 4; ++i) {
        const int ra = wr + i * 16 + lr;
        af[i] = *(const bf16x8*)(As + ra * 128 + swz16((kk >> 3) + quad, ra));
      }
#pragma unroll
      for (int j = 0; j < 2; ++j) {
        const int rb = wc + j * 16 + lr;
        bfr[j] = *(const bf16x8*)(Bs + rb * 128 + swz16((kk >> 3) + quad, rb));
      }
#pragma unroll
      for (int i = 0; i < 4; ++i)
#pragma unroll
        for (int j = 0; j < 2; ++j)
          acc[i][j] = __builtin_amdgcn_mfma_f32_16x16x32_bf16(af[i], bfr[j], acc[i][j], 0, 0, 0);
    }

    // epilogue: exp, store E, per-column sums (register-only)
#pragma unroll
    for (int j = 0; j < 2; ++j) {
      const int n = nstrip + nt * 64 + wc + j * 16 + lr;
      float l_loc = 0.f;
#pragma unroll
      for (int i = 0; i < 4; ++i) {
        const int mb = m0 + wr + i * 16 + quad * 4;
#pragma unroll
        for (int r = 0; r < 4; ++r) {
          bf16 ev = (bf16)__expf(acc[i][j][r] * scale);
          C[(long long)(mb + r) * SEQ + n] = ev;
          l_loc += (float)ev;  // stats from the bf16-ROUNDED value PV reads
        }
      }
      l_loc += __shfl_xor(l_loc, 16, 64);  // sum the 4 quads -> 64 rows
      l_loc += __shfl_xor(l_loc, 32, 64);
      if (quad == 0)
        lpart[((long long)h * 32 + blockIdx.y * 2 + (wave >> 1)) * SEQ + n] = l_loc;
    }
  }
}

// merge 32 rowblock partial sums -> r[h][t] = 1/sum
__global__ void sm_sum(const float* __restrict__ lp, float* __restrict__ rvec) {
  const int i = blockIdx.x * 256 + threadIdx.x;  // over NHEADS*SEQ
  const int h = i >> 11, t = i & (SEQ - 1);
  float l = 0.f;
#pragma unroll
  for (int rb = 0; rb < 32; ++rb)
    l += lp[((long long)h * 32 + rb) * SEQ + t];
  rvec[i] = 1.f / l;
}

// scale v^T rows by r[h][t] in place: vt[cg][t] *= r[cg>>7][t]
__global__ void vscale(bf16* __restrict__ vt, const float* __restrict__ rvec) {
  const int cg = blockIdx.y;
  const int t0 = threadIdx.x * 8;
  const float* r = rvec + (cg >> 7) * SEQ;
  bf16x8 v = *(const bf16x8*)(vt + (long long)cg * SEQ + t0);
#pragma unroll
  for (int e = 0; e < 8; ++e) v[e] = (bf16)((float)v[e] * r[t0 + e]);
  *(bf16x8*)(vt + (long long)cg * SEQ + t0) = v;
}

// ---------------------------------------------------------------------------
// PV (pure GEMM): O[s, h*128+c] = sum_t E[h][s][t] * vts[h*128+c][t]
// Tile 64x128, 4 waves of 32x64 (acc 2x4). grid (SEQ/64, NHEADS).
// ---------------------------------------------------------------------------
__global__ __launch_bounds__(256) void pv_gemm(
    const bf16* __restrict__ Sc, const bf16* __restrict__ VT,
    bf16* __restrict__ O) {
  const int h = blockIdx.y;
  const int m0 = blockIdx.x * 64;
  const bf16* A = Sc + (long long)h * SEQ * SEQ;
  const bf16* B = VT + (long long)h * DKH * SEQ;

  __shared__ __align__(16) bf16 As[64 * 64];
  __shared__ __align__(16) bf16 Bs[128 * 64];

  const int tid = threadIdx.x;
  const int wave = tid >> 6;
  const int lane = tid & 63;
  const int srow = wave * 8 + (lane >> 3);
  const int scol = ((lane & 7) ^ (lane >> 3)) * 8;
  const int wr = (wave >> 1) * 32;
  const int wc = (wave & 1) * 64;
  const int lr = lane & 15;
  const int quad = lane >> 4;

  const bf16* ag = A + (long long)(m0 + srow) * SEQ + scol;
  const bf16* bg = B + (long long)srow * SEQ + scol;

  f32x4 acc[2][4];
#pragma unroll
  for (int i = 0; i < 2; ++i)
#pragma unroll
    for (int j = 0; j < 4; ++j) {
      acc[i][j][0] = 0.f; acc[i][j][1] = 0.f;
      acc[i][j][2] = 0.f; acc[i][j][3] = 0.f;
    }

  for (int kt = 0; kt < SEQ; kt += 64) {
#pragma unroll
    for (int i = 0; i < 2; ++i)
      async_copy16(ag + kt + (long long)i * 32 * SEQ, As + (i * 32 + wave * 8) * 64);
#pragma unroll
    for (int i = 0; i < 4; ++i)
      async_copy16(bg + kt + (long long)i * 32 * SEQ, Bs + (i * 32 + wave * 8) * 64);
    __syncthreads();
#pragma unroll
    for (int kk = 0; kk < 64; kk += 32) {
      bf16x8 af[2], bfr[4];
#pragma unroll
      for (int i = 0; i < 2; ++i) {
        const int ra = wr + i * 16 + lr;
        af[i] = *(const bf16x8*)(As + ra * 64 + swz((kk >> 3) + quad, ra));
      }
#pragma unroll
      for (int j = 0; j < 4; ++j) {
        const int rb = wc + j * 16 + lr;
        bfr[j] = *(const bf16x8*)(Bs + rb * 64 + swz((kk >> 3) + quad, rb));
      }
#pragma unroll
      for (int i = 0; i < 2; ++i)
#pragma unroll
        for (int j = 0; j < 4; ++j)
          acc[i][j] = __builtin_amdgcn_mfma_f32_16x16x32_bf16(af[i], bfr[j], acc[i][j], 0, 0, 0);
    }
    __syncthreads();
  }

#pragma unroll
  for (int j = 0; j < 4; ++j) {
    const int c = h * DKH + wc + j * 16 + lr;
#pragma unroll
    for (int i = 0; i < 2; ++i) {
      const int mb = m0 + wr + i * 16 + quad * 4;
#pragma unroll
      for (int r = 0; r < 4; ++r)
        O[(long long)(mb + r) * DMODEL + c] = (bf16)acc[i][j][r];
    }
  }
}

// split-K=2 reduce for out-proj: out[i] = p0[i] + p1[i] + bo[i % 2048], x4 vec
__global__ void reduce_bias(const float* __restrict__ p, const float* __restrict__ bo,
                            float* __restrict__ out) {
  const long long i = ((long long)blockIdx.x * 256 + threadIdx.x) * 4;
  const float4 a = *(const float4*)(p + i);
  const float4 b = *(const float4*)(p + (long long)SEQ * DMODEL + i);
  const float4 bb = *(const float4*)(bo + (i & (DMODEL - 1)));
  float4 o;
  o.x = a.x + b.x + bb.x; o.y = a.y + b.y + bb.y;
  o.z = a.z + b.z + bb.z; o.w = a.w + b.w + bb.w;
  *(float4*)(out + i) = o;
}

// ---------------------------------------------------------------------------
// Fused prep: one launch, uniform 256-thread blocks, partitioned by blockIdx.x:
//  [0,12288):       cvt q/k/v fp32->bf16 (4096 blocks each, 4 elems/thread)
//  [12288,24576):   Wq/Wk/Wv transpose [2048][128] -> bf16 [128][2048] (z<48)
//  [24576,28672):   Wo transpose [2048][2048] -> bf16 Wo^T
//  [28672,28680):   bias pack
// ---------------------------------------------------------------------------
__global__ __launch_bounds__(256) void prep(
    const float* __restrict__ q, const float* __restrict__ k,
    const float* __restrict__ v,
    const float* __restrict__ Wq, const float* __restrict__ Wk,
    const float* __restrict__ Wv, const float* __restrict__ Wo,
    const float* __restrict__ bq, const float* __restrict__ bk,
    const float* __restrict__ bv,
    bf16* __restrict__ Qb, bf16* __restrict__ Wt, bf16* __restrict__ Wot,
    float* __restrict__ biasQKV) {
  __shared__ float tile[32][33];
  const long long elems = (long long)SEQ * DMODEL;
  const int id = blockIdx.x;
  const int tid = threadIdx.x;

  if (id < 12288) {  // cvt
    const float* src = (id < 4096) ? q : (id < 8192) ? k : v;
    const int t = id >> 12;
    const long long i = (long long)(id & 4095) * 1024 + tid * 4;
    const float4 vv = *(const float4*)(src + i);
    bf16x4 o;
    o[0] = (bf16)vv.x; o[1] = (bf16)vv.y; o[2] = (bf16)vv.z; o[3] = (bf16)vv.w;
    *(bf16x4*)(Qb + (long long)t * elems + i) = o;
    return;
  }
  const int tx = tid & 31, ty = tid >> 5;
  if (id < 24576) {  // Wq/Wk/Wv transpose
    const int rel = id - 12288;
    const int z = rel >> 8;             // 0..47
    const int inner = rel & 255;
    const int bx = inner & 3;           // DKH/32
    const int by = inner >> 2;          // DMODEL/32
    const int g = z >> 4, hh = z & 15;
    const float* in = (g == 0 ? Wq : (g == 1 ? Wk : Wv)) + (long long)hh * DMODEL * DKH;
    bf16* o = Wt + (long long)z * DMODEL * DKH;
    const int c0 = bx * 32, r0 = by * 32;
#pragma unroll
    for (int j = 0; j < 32; j += 8)
      tile[ty + j][tx] = in[(long long)(r0 + ty + j) * DKH + c0 + tx];
    __syncthreads();
#pragma unroll
    for (int j = 0; j < 32; j += 8)
      o[(long long)(c0 + ty + j) * DMODEL + r0 + tx] = (bf16)tile[tx][ty + j];
    return;
  }
  if (id < 28672) {  // Wo transpose
    const int rel = id - 24576;
    const int bx = rel & 63, by = rel >> 6;
    const int c0 = bx * 32, r0 = by * 32;
#pragma unroll
    for (int j = 0; j < 32; j += 8)
      tile[ty + j][tx] = Wo[(long long)(r0 + ty + j) * DMODEL + c0 + tx];
    __syncthreads();
#pragma unroll
    for (int j = 0; j < 32; j += 8)
      Wot[(long long)(c0 + ty + j) * DMODEL + r0 + tx] = (bf16)tile[tx][ty + j];
    return;
  }
  {  // bias pack
    const int i = (id - 28672) * 256 + tid;
    if (i < NHEADS * DKH) {
      biasQKV[i] = bq[i];
      biasQKV[NHEADS * DKH + i] = bk[i];
      biasQKV[2 * NHEADS * DKH + i] = bv[i];
    }
  }
}

// ---------------------------------------------------------------------------
extern "C" void kernel_launch(void* const* d_in, const int* in_sizes, int n_in,
                              void* d_out, int out_size, void* d_ws, size_t ws_size,
                              hipStream_t stream) {
  const float* query = (const float*)d_in[0];
  const float* key_  = (const float*)d_in[1];
  const float* value = (const float*)d_in[2];
  const float* Wq = (const float*)d_in[3];
  const float* bq = (const float*)d_in[4];
  const float* Wk = (const float*)d_in[5];
  const float* bk = (const float*)d_in[6];
  const float* Wv = (const float*)d_in[7];
  const float* bv = (const float*)d_in[8];
  const float* Wo = (const float*)d_in[9];
  const float* bo = (const float*)d_in[10];
  float* out = (float*)d_out;

  const long long elems = (long long)SEQ * DMODEL;  // 4M
  const long long SZB = elems * 2;                  // 8MB

  char* ws = (char*)d_ws;
  bf16* Qb = (bf16*)ws;              // 3 x SZB (dead after projection)
  bf16* Wt = (bf16*)(ws + 3 * SZB);  // 3 x SZB (dead after projection)
  bf16* scores = (bf16*)ws;          // 128MB (E = exp(score)), reuses Qb/Wt
  float* Opart = (float*)ws;         // 2 x 16MB fp32, reuses scores (E dead)
  char* p = ws + (long long)NHEADS * SEQ * SEQ * 2;
  float* biasQKV = (float*)p; p += 32 * 1024;
  bf16* Wot   = (bf16*)p; p += SZB;
  bf16* qkv   = (bf16*)p; p += 3 * SZB;   // v third unused (v^T written directly)
  bf16* vt    = (bf16*)p; p += SZB;
  bf16* heads = (bf16*)p; p += SZB;
  float* lpart = (float*)p; p += (long long)NHEADS * 32 * SEQ * 4;  // 4MB
  float* rvec  = (float*)p; p += (long long)NHEADS * SEQ * 4;       // 128KB
  if ((size_t)(p - ws) > ws_size) return;

  // 1) fused prep (converts + weight transposes + bias pack), one launch
  prep<<<28680, 256, 0, stream>>>(query, key_, value, Wq, Wk, Wv, Wo,
                                  bq, bk, bv, Qb, Wt, Wot, biasQKV);

  // 2) QKV projections (batched z=3); z==2 (v) written directly as v^T
  gemm_bt<bf16, true><<<dim3(16, 16, 3), 256, 0, stream>>>(
      Qb, Wt, biasQKV, qkv, SEQ, DMODEL, DMODEL, DMODEL, DMODEL, DMODEL, 1.f,
      elems, elems, elems, (long long)DMODEL, vt);

  // 3) E = exp(QK^T/sqrt(dk)) + column partial sums (A-resident strip kernel)
  qk_exp<<<dim3(4, 16, NHEADS), 256, 0, stream>>>(qkv, qkv + elems, scores, lpart);

  // 4) r[h][t] = 1/sum
  sm_sum<<<NHEADS * SEQ / 256, 256, 0, stream>>>(lpart, rvec);

  // 5) fold r into v^T (in place)
  vscale<<<dim3(1, DMODEL), 256, 0, stream>>>(vt, rvec);

  // 6) PV: pure GEMM
  pv_gemm<<<dim3(SEQ / 64, NHEADS), 256, 0, stream>>>(scores, vt, heads);

  // 7) out-proj, split-K=2 (z = K-half), fp32 partials into Opart
  gemm_bt<float, false><<<dim3(16, 16, 2), 256, 0, stream>>>(
      heads, Wot, nullptr, Opart, SEQ, DMODEL, 1024, DMODEL, DMODEL, DMODEL, 1.f,
      1024, 1024, elems, 0, nullptr);

  // 8) reduce partials + bias -> fp32 out
  reduce_bias<<<elems / 1024, 256, 0, stream>>>(Opart, bo, out);
}

// Round 7
// 347.046 us; speedup vs baseline: 1.0518x; 1.0518x over previous
//
#include <hip/hip_runtime.h>

#define SEQ 2048
#define DMODEL 2048
#define NHEADS 16
#define DKH 128

typedef __bf16 bf16;
typedef __attribute__((ext_vector_type(8))) __bf16 bf16x8;
typedef __attribute__((ext_vector_type(4))) __bf16 bf16x4;
typedef __attribute__((ext_vector_type(4))) float f32x4;

#define AS1 __attribute__((address_space(1)))
#define AS3 __attribute__((address_space(3)))

__device__ __forceinline__ void async_copy16(const void* g, void* l) {
  __builtin_amdgcn_global_load_lds((AS1 void*)(unsigned long long)g,
                                   (AS3 void*)l, 16, 0, 0);
}

// XOR-swizzle for 64-wide (8-chunk) LDS rows: slot = chunk ^ (row&7)
__device__ __forceinline__ int swz(int chunk, int row) {
  return (chunk ^ (row & 7)) << 3;
}
// XOR-swizzle for 128-wide (16-chunk) LDS rows: slot = chunk ^ (row&15)
__device__ __forceinline__ int swz16(int chunk, int row) {
  return (chunk ^ (row & 15)) << 3;
}

// ---------------------------------------------------------------------------
// Generic bf16 GEMM, "BT" pattern: C[m,n] = scale * sum_k A[m,k]*B[n,k] (+bias[n])
// 128x128 tile, BK=64, 4 waves of 64x64 via 16x16x32 MFMA, swizzled LDS.
// (R4 epilogue restored: no transposed-write path — it cost 8 VGPRs and
//  ~1 wave/SIMD of occupancy on the hot dispatch, m5 post-mortem.)
// ---------------------------------------------------------------------------
template <typename OutT, bool BIAS>
__global__ __launch_bounds__(256) void gemm_bt(
    const bf16* __restrict__ A, const bf16* __restrict__ B,
    const float* __restrict__ bias, OutT* __restrict__ C,
    int M, int N, int K, int lda, int ldb, int ldo, float scale,
    long long sA, long long sB, long long sC, long long sBias) {
  A += (long long)blockIdx.z * sA;
  B += (long long)blockIdx.z * sB;
  C += (long long)blockIdx.z * sC;
  const float* biasp = BIAS ? (bias + (long long)blockIdx.z * sBias) : nullptr;

  const int m0 = blockIdx.y * 128;
  const int n0 = blockIdx.x * 128;

  __shared__ __align__(16) bf16 As[128 * 64];
  __shared__ __align__(16) bf16 Bs[128 * 64];

  const int tid = threadIdx.x;
  const int wave = tid >> 6;
  const int lane = tid & 63;
  const int srow = wave * 8 + (lane >> 3);
  const int scol = ((lane & 7) ^ (lane >> 3)) * 8;  // swizzled source chunk
  const int wr = (wave >> 1) * 64;
  const int wc = (wave & 1) * 64;
  const int lr = lane & 15;
  const int quad = lane >> 4;

  const bf16* ag = A + (long long)(m0 + srow) * lda + scol;
  const bf16* bg = B + (long long)(n0 + srow) * ldb + scol;

  f32x4 acc[4][4];
#pragma unroll
  for (int i = 0; i < 4; ++i)
#pragma unroll
    for (int j = 0; j < 4; ++j) {
      acc[i][j][0] = 0.f; acc[i][j][1] = 0.f;
      acc[i][j][2] = 0.f; acc[i][j][3] = 0.f;
    }

  for (int kt = 0; kt < K; kt += 64) {
#pragma unroll
    for (int i = 0; i < 4; ++i) {
      async_copy16(ag + kt + (long long)i * 32 * lda, As + (i * 32 + wave * 8) * 64);
      async_copy16(bg + kt + (long long)i * 32 * ldb, Bs + (i * 32 + wave * 8) * 64);
    }
    __syncthreads();
#pragma unroll
    for (int kk = 0; kk < 64; kk += 32) {
      bf16x8 af[4], bfr[4];
#pragma unroll
      for (int i = 0; i < 4; ++i) {
        const int ra = wr + i * 16 + lr;
        const int rb = wc + i * 16 + lr;
        af[i]  = *(const bf16x8*)(As + ra * 64 + swz((kk >> 3) + quad, ra));
        bfr[i] = *(const bf16x8*)(Bs + rb * 64 + swz((kk >> 3) + quad, rb));
      }
#pragma unroll
      for (int i = 0; i < 4; ++i)
#pragma unroll
        for (int j = 0; j < 4; ++j)
          acc[i][j] = __builtin_amdgcn_mfma_f32_16x16x32_bf16(af[i], bfr[j], acc[i][j], 0, 0, 0);
    }
    __syncthreads();
  }

#pragma unroll
  for (int j = 0; j < 4; ++j) {
    const int n = n0 + wc + j * 16 + lr;
    const float bv = BIAS ? biasp[n] : 0.f;
#pragma unroll
    for (int i = 0; i < 4; ++i) {
      const int mb = m0 + wr + i * 16 + quad * 4;
#pragma unroll
      for (int r = 0; r < 4; ++r)
        C[(long long)(mb + r) * ldo + n] = (OutT)(acc[i][j][r] * scale + bv);
    }
  }
}

// ---------------------------------------------------------------------------
// QK^T -> E = exp(score/sqrt(dk)) bf16 + per-column (over s) partial sums.
// A-tile 128x128 (32KB) resident; loop 8 B-tiles of 64 rows (16KB) over a
// 512-wide strip. LDS 48KB -> 3 blocks/CU. grid (4, 16, 16).
// ---------------------------------------------------------------------------
__global__ __launch_bounds__(256) void qk_exp(
    const bf16* __restrict__ q, const bf16* __restrict__ k,
    bf16* __restrict__ E, float* __restrict__ lpart) {
  const int h = blockIdx.z;
  const int m0 = blockIdx.y * 128;
  const int nstrip = blockIdx.x * 512;
  const bf16* A = q + (long long)h * DKH;
  const bf16* B = k + (long long)h * DKH;
  bf16* C = E + (long long)h * SEQ * SEQ;

  __shared__ __align__(16) bf16 As[128 * 128];  // 32KB
  __shared__ __align__(16) bf16 Bs[64 * 128];   // 16KB

  const int tid = threadIdx.x;
  const int wave = tid >> 6;
  const int lane = tid & 63;
  const int wr = (wave >> 1) * 64;  // A-row half
  const int wc = (wave & 1) * 32;   // B-col quarter (of 64)
  const int lr = lane & 15;
  const int quad = lane >> 4;
  const float scale = 0.08838834764831845f;  // 1/sqrt(128)

  // stage A-tile once (resident across all 8 B-tiles)
#pragma unroll
  for (int it = 0; it < 8; ++it) {
    const int row = wave * 32 + it * 4 + (lane >> 4);
    const int chunk = (lane & 15) ^ (row & 15);
    async_copy16(A + (long long)(m0 + row) * DMODEL + chunk * 8,
                 As + (wave * 32 + it * 4) * 128);
  }

  for (int nt = 0; nt < 8; ++nt) {
    if (nt) __syncthreads();  // protect Bs while other waves still read
#pragma unroll
    for (int it = 0; it < 4; ++it) {
      const int row = wave * 16 + it * 4 + (lane >> 4);
      const int chunk = (lane & 15) ^ (row & 15);
      async_copy16(B + (long long)(nstrip + nt * 64 + row) * DMODEL + chunk * 8,
                   Bs + (wave * 16 + it * 4) * 128);
    }
    __syncthreads();  // drains A (nt=0) and B staging

    f32x4 acc[4][2];
#pragma unroll
    for (int i = 0; i < 4; ++i)
#pragma unroll
      for (int j = 0; j < 2; ++j) {
        acc[i][j][0] = 0.f; acc[i][j][1] = 0.f;
        acc[i][j][2] = 0.f; acc[i][j][3] = 0.f;
      }

#pragma unroll
    for (int kk = 0; kk < 128; kk += 32) {
      bf16x8 af[4], bfr[2];
#pragma unroll
      for (int i = 0; i < 4; ++i) {
        const int ra = wr + i * 16 + lr;
        af[i] = *(const bf16x8*)(As + ra * 128 + swz16((kk >> 3) + quad, ra));
      }
#pragma unroll
      for (int j = 0; j < 2; ++j) {
        const int rb = wc + j * 16 + lr;
        bfr[j] = *(const bf16x8*)(Bs + rb * 128 + swz16((kk >> 3) + quad, rb));
      }
#pragma unroll
      for (int i = 0; i < 4; ++i)
#pragma unroll
        for (int j = 0; j < 2; ++j)
          acc[i][j] = __builtin_amdgcn_mfma_f32_16x16x32_bf16(af[i], bfr[j], acc[i][j], 0, 0, 0);
    }

    // epilogue: exp, store E, per-column sums (register-only)
#pragma unroll
    for (int j = 0; j < 2; ++j) {
      const int n = nstrip + nt * 64 + wc + j * 16 + lr;
      float l_loc = 0.f;
#pragma unroll
      for (int i = 0; i < 4; ++i) {
        const int mb = m0 + wr + i * 16 + quad * 4;
#pragma unroll
        for (int r = 0; r < 4; ++r) {
          bf16 ev = (bf16)__expf(acc[i][j][r] * scale);
          C[(long long)(mb + r) * SEQ + n] = ev;
          l_loc += (float)ev;  // stats from the bf16-ROUNDED value PV reads
        }
      }
      l_loc += __shfl_xor(l_loc, 16, 64);  // sum the 4 quads -> 64 rows
      l_loc += __shfl_xor(l_loc, 32, 64);
      if (quad == 0)
        lpart[((long long)h * 32 + blockIdx.y * 2 + (wave >> 1)) * SEQ + n] = l_loc;
    }
  }
}

// merge 32 rowblock partial sums -> r[h][t] = 1/sum
__global__ void sm_sum(const float* __restrict__ lp, float* __restrict__ rvec) {
  const int i = blockIdx.x * 256 + threadIdx.x;  // over NHEADS*SEQ
  const int h = i >> 11, t = i & (SEQ - 1);
  float l = 0.f;
#pragma unroll
  for (int rb = 0; rb < 32; ++rb)
    l += lp[((long long)h * 32 + rb) * SEQ + t];
  rvec[i] = 1.f / l;
}

// scale v^T rows by r[h][t] in place: vt[cg][t] *= r[cg>>7][t]
__global__ void vscale(bf16* __restrict__ vt, const float* __restrict__ rvec) {
  const int cg = blockIdx.y;
  const int t0 = threadIdx.x * 8;
  const float* r = rvec + (cg >> 7) * SEQ;
  bf16x8 v = *(const bf16x8*)(vt + (long long)cg * SEQ + t0);
#pragma unroll
  for (int e = 0; e < 8; ++e) v[e] = (bf16)((float)v[e] * r[t0 + e]);
  *(bf16x8*)(vt + (long long)cg * SEQ + t0) = v;
}

// ---------------------------------------------------------------------------
// PV (pure GEMM): O[s, h*128+c] = sum_t E[h][s][t] * vts[h*128+c][t]
// Tile 64x128, 4 waves of 32x64 (acc 2x4). grid (SEQ/64, NHEADS).
// ---------------------------------------------------------------------------
__global__ __launch_bounds__(256) void pv_gemm(
    const bf16* __restrict__ Sc, const bf16* __restrict__ VT,
    bf16* __restrict__ O) {
  const int h = blockIdx.y;
  const int m0 = blockIdx.x * 64;
  const bf16* A = Sc + (long long)h * SEQ * SEQ;
  const bf16* B = VT + (long long)h * DKH * SEQ;

  __shared__ __align__(16) bf16 As[64 * 64];
  __shared__ __align__(16) bf16 Bs[128 * 64];

  const int tid = threadIdx.x;
  const int wave = tid >> 6;
  const int lane = tid & 63;
  const int srow = wave * 8 + (lane >> 3);
  const int scol = ((lane & 7) ^ (lane >> 3)) * 8;
  const int wr = (wave >> 1) * 32;
  const int wc = (wave & 1) * 64;
  const int lr = lane & 15;
  const int quad = lane >> 4;

  const bf16* ag = A + (long long)(m0 + srow) * SEQ + scol;
  const bf16* bg = B + (long long)srow * SEQ + scol;

  f32x4 acc[2][4];
#pragma unroll
  for (int i = 0; i < 2; ++i)
#pragma unroll
    for (int j = 0; j < 4; ++j) {
      acc[i][j][0] = 0.f; acc[i][j][1] = 0.f;
      acc[i][j][2] = 0.f; acc[i][j][3] = 0.f;
    }

  for (int kt = 0; kt < SEQ; kt += 64) {
#pragma unroll
    for (int i = 0; i < 2; ++i)
      async_copy16(ag + kt + (long long)i * 32 * SEQ, As + (i * 32 + wave * 8) * 64);
#pragma unroll
    for (int i = 0; i < 4; ++i)
      async_copy16(bg + kt + (long long)i * 32 * SEQ, Bs + (i * 32 + wave * 8) * 64);
    __syncthreads();
#pragma unroll
    for (int kk = 0; kk < 64; kk += 32) {
      bf16x8 af[2], bfr[4];
#pragma unroll
      for (int i = 0; i < 2; ++i) {
        const int ra = wr + i * 16 + lr;
        af[i] = *(const bf16x8*)(As + ra * 64 + swz((kk >> 3) + quad, ra));
      }
#pragma unroll
      for (int j = 0; j < 4; ++j) {
        const int rb = wc + j * 16 + lr;
        bfr[j] = *(const bf16x8*)(Bs + rb * 64 + swz((kk >> 3) + quad, rb));
      }
#pragma unroll
      for (int i = 0; i < 2; ++i)
#pragma unroll
        for (int j = 0; j < 4; ++j)
          acc[i][j] = __builtin_amdgcn_mfma_f32_16x16x32_bf16(af[i], bfr[j], acc[i][j], 0, 0, 0);
    }
    __syncthreads();
  }

#pragma unroll
  for (int j = 0; j < 4; ++j) {
    const int c = h * DKH + wc + j * 16 + lr;
#pragma unroll
    for (int i = 0; i < 2; ++i) {
      const int mb = m0 + wr + i * 16 + quad * 4;
#pragma unroll
      for (int r = 0; r < 4; ++r)
        O[(long long)(mb + r) * DMODEL + c] = (bf16)acc[i][j][r];
    }
  }
}

// split-K=2 reduce for out-proj: out[i] = p0[i] + p1[i] + bo[i % 2048], x4 vec
__global__ void reduce_bias(const float* __restrict__ p, const float* __restrict__ bo,
                            float* __restrict__ out) {
  const long long i = ((long long)blockIdx.x * 256 + threadIdx.x) * 4;
  const float4 a = *(const float4*)(p + i);
  const float4 b = *(const float4*)(p + (long long)SEQ * DMODEL + i);
  const float4 bb = *(const float4*)(bo + (i & (DMODEL - 1)));
  float4 o;
  o.x = a.x + b.x + bb.x; o.y = a.y + b.y + bb.y;
  o.z = a.z + b.z + bb.z; o.w = a.w + b.w + bb.w;
  *(float4*)(out + i) = o;
}

// ---------------------------------------------------------------------------
// Fused prep: one launch, uniform 256-thread blocks, partitioned by blockIdx.x:
//  [0,12288):       cvt q/k/v fp32->bf16 (4096 blocks each, 4 elems/thread)
//  [12288,24576):   Wq/Wk/Wv transpose [2048][128] -> bf16 [128][2048] (z<48)
//  [24576,28672):   Wo transpose [2048][2048] -> bf16 Wo^T
//  [28672,28680):   bias pack
// ---------------------------------------------------------------------------
__global__ __launch_bounds__(256) void prep(
    const float* __restrict__ q, const float* __restrict__ k,
    const float* __restrict__ v,
    const float* __restrict__ Wq, const float* __restrict__ Wk,
    const float* __restrict__ Wv, const float* __restrict__ Wo,
    const float* __restrict__ bq, const float* __restrict__ bk,
    const float* __restrict__ bv,
    bf16* __restrict__ Qb, bf16* __restrict__ Wt, bf16* __restrict__ Wot,
    float* __restrict__ biasQKV) {
  __shared__ float tile[32][33];
  const long long elems = (long long)SEQ * DMODEL;
  const int id = blockIdx.x;
  const int tid = threadIdx.x;

  if (id < 12288) {  // cvt
    const float* src = (id < 4096) ? q : (id < 8192) ? k : v;
    const int t = id >> 12;
    const long long i = (long long)(id & 4095) * 1024 + tid * 4;
    const float4 vv = *(const float4*)(src + i);
    bf16x4 o;
    o[0] = (bf16)vv.x; o[1] = (bf16)vv.y; o[2] = (bf16)vv.z; o[3] = (bf16)vv.w;
    *(bf16x4*)(Qb + (long long)t * elems + i) = o;
    return;
  }
  const int tx = tid & 31, ty = tid >> 5;
  if (id < 24576) {  // Wq/Wk/Wv transpose
    const int rel = id - 12288;
    const int z = rel >> 8;             // 0..47
    const int inner = rel & 255;
    const int bx = inner & 3;           // DKH/32
    const int by = inner >> 2;          // DMODEL/32
    const int g = z >> 4, hh = z & 15;
    const float* in = (g == 0 ? Wq : (g == 1 ? Wk : Wv)) + (long long)hh * DMODEL * DKH;
    bf16* o = Wt + (long long)z * DMODEL * DKH;
    const int c0 = bx * 32, r0 = by * 32;
#pragma unroll
    for (int j = 0; j < 32; j += 8)
      tile[ty + j][tx] = in[(long long)(r0 + ty + j) * DKH + c0 + tx];
    __syncthreads();
#pragma unroll
    for (int j = 0; j < 32; j += 8)
      o[(long long)(c0 + ty + j) * DMODEL + r0 + tx] = (bf16)tile[tx][ty + j];
    return;
  }
  if (id < 28672) {  // Wo transpose
    const int rel = id - 24576;
    const int bx = rel & 63, by = rel >> 6;
    const int c0 = bx * 32, r0 = by * 32;
#pragma unroll
    for (int j = 0; j < 32; j += 8)
      tile[ty + j][tx] = Wo[(long long)(r0 + ty + j) * DMODEL + c0 + tx];
    __syncthreads();
#pragma unroll
    for (int j = 0; j < 32; j += 8)
      Wot[(long long)(c0 + ty + j) * DMODEL + r0 + tx] = (bf16)tile[tx][ty + j];
    return;
  }
  {  // bias pack
    const int i = (id - 28672) * 256 + tid;
    if (i < NHEADS * DKH) {
      biasQKV[i] = bq[i];
      biasQKV[NHEADS * DKH + i] = bk[i];
      biasQKV[2 * NHEADS * DKH + i] = bv[i];
    }
  }
}

// v -> v^T (bf16 in, bf16 out), 32x32 tiles
__global__ void transpose_v(const bf16* __restrict__ in, bf16* __restrict__ out) {
  __shared__ float tile[32][33];
  const int c0 = blockIdx.x * 32, r0 = blockIdx.y * 32;
  const int tx = threadIdx.x, ty = threadIdx.y;
#pragma unroll
  for (int j = 0; j < 32; j += 8)
    tile[ty + j][tx] = (float)in[(long long)(r0 + ty + j) * DMODEL + c0 + tx];
  __syncthreads();
#pragma unroll
  for (int j = 0; j < 32; j += 8)
    out[(long long)(c0 + ty + j) * SEQ + r0 + tx] = (bf16)tile[tx][ty + j];
}

// ---------------------------------------------------------------------------
extern "C" void kernel_launch(void* const* d_in, const int* in_sizes, int n_in,
                              void* d_out, int out_size, void* d_ws, size_t ws_size,
                              hipStream_t stream) {
  const float* query = (const float*)d_in[0];
  const float* key_  = (const float*)d_in[1];
  const float* value = (const float*)d_in[2];
  const float* Wq = (const float*)d_in[3];
  const float* bq = (const float*)d_in[4];
  const float* Wk = (const float*)d_in[5];
  const float* bk = (const float*)d_in[6];
  const float* Wv = (const float*)d_in[7];
  const float* bv = (const float*)d_in[8];
  const float* Wo = (const float*)d_in[9];
  const float* bo = (const float*)d_in[10];
  float* out = (float*)d_out;

  const long long elems = (long long)SEQ * DMODEL;  // 4M
  const long long SZB = elems * 2;                  // 8MB

  char* ws = (char*)d_ws;
  bf16* Qb = (bf16*)ws;              // 3 x SZB (dead after projection)
  bf16* Wt = (bf16*)(ws + 3 * SZB);  // 3 x SZB (dead after projection)
  bf16* scores = (bf16*)ws;          // 128MB (E = exp(score)), reuses Qb/Wt
  float* Opart = (float*)ws;         // 2 x 16MB fp32, reuses scores (E dead)
  char* p = ws + (long long)NHEADS * SEQ * SEQ * 2;
  float* biasQKV = (float*)p; p += 32 * 1024;
  bf16* Wot   = (bf16*)p; p += SZB;
  bf16* qkv   = (bf16*)p; p += 3 * SZB;
  bf16* vt    = (bf16*)p; p += SZB;
  bf16* heads = (bf16*)p; p += SZB;
  float* lpart = (float*)p; p += (long long)NHEADS * 32 * SEQ * 4;  // 4MB
  float* rvec  = (float*)p; p += (long long)NHEADS * SEQ * 4;       // 128KB
  if ((size_t)(p - ws) > ws_size) return;

  // 1) fused prep (converts + weight transposes + bias pack), one launch
  prep<<<28680, 256, 0, stream>>>(query, key_, value, Wq, Wk, Wv, Wo,
                                  bq, bk, bv, Qb, Wt, Wot, biasQKV);

  // 2) QKV projections (batched z=3)
  gemm_bt<bf16, true><<<dim3(16, 16, 3), 256, 0, stream>>>(
      Qb, Wt, biasQKV, qkv, SEQ, DMODEL, DMODEL, DMODEL, DMODEL, DMODEL, 1.f,
      elems, elems, elems, (long long)DMODEL);

  // 3) v -> v^T (separate kernel; fusing into the GEMM epilogue cost 8 VGPRs
  //    and ~24 us on the hot dispatch — R5 post-mortem)
  transpose_v<<<dim3(DMODEL / 32, SEQ / 32), dim3(32, 8), 0, stream>>>(
      qkv + 2 * elems, vt);

  // 4) E = exp(QK^T/sqrt(dk)) + column partial sums (A-resident strip kernel)
  qk_exp<<<dim3(4, 16, NHEADS), 256, 0, stream>>>(qkv, qkv + elems, scores, lpart);

  // 5) r[h][t] = 1/sum
  sm_sum<<<NHEADS * SEQ / 256, 256, 0, stream>>>(lpart, rvec);

  // 6) fold r into v^T (in place)
  vscale<<<dim3(1, DMODEL), 256, 0, stream>>>(vt, rvec);

  // 7) PV: pure GEMM
  pv_gemm<<<dim3(SEQ / 64, NHEADS), 256, 0, stream>>>(scores, vt, heads);

  // 8) out-proj, split-K=2 (z = K-half), fp32 partials into Opart
  gemm_bt<float, false><<<dim3(16, 16, 2), 256, 0, stream>>>(
      heads, Wot, nullptr, Opart, SEQ, DMODEL, 1024, DMODEL, DMODEL, DMODEL, 1.f,
      1024, 1024, elems, 0);

  // 9) reduce partials + bias -> fp32 out
  reduce_bias<<<elems / 1024, 256, 0, stream>>>(Opart, bo, out);
}